// Round 7
// baseline (275.733 us; speedup 1.0000x reference)
//
#include <hip/hip_runtime.h>
#include <math.h>

#define BATCH 4
#define TSEQ 2048
#define CDIM 1024
#define NHEAD 16
#define HDIM 64
#define M_ROWS (BATCH * TSEQ)   // 8192

typedef float f32x4 __attribute__((ext_vector_type(4)));
typedef __bf16 bf16x8 __attribute__((ext_vector_type(8)));
typedef unsigned int u32x4 __attribute__((ext_vector_type(4)));

typedef const __attribute__((address_space(1))) void gas_void;
typedef __attribute__((address_space(3))) void las_void;

static __device__ __forceinline__ unsigned short f2bf(float f) {
    unsigned int x = __float_as_uint(f);
    x += 0x7fffu + ((x >> 16) & 1u);
    return (unsigned short)(x >> 16);
}

// ---------------- merged prep: 3x fp32->bf16 cvt + RoPE table -----------------
// block ranges: [0,4096) x, [4096,5632) w_attn, [5632,6144) w_proj, [6144,6400) rope
__global__ void prep_kernel(const float* __restrict__ x, unsigned short* __restrict__ xb,
                            const float* __restrict__ wa, unsigned short* __restrict__ wab,
                            const float* __restrict__ wp, unsigned short* __restrict__ wpb,
                            float* __restrict__ cosT, float* __restrict__ sinT) {
    int blk = blockIdx.x;
    if (blk < 6144) {
        const float* in;
        unsigned short* out;
        int base;
        if (blk < 4096)      { in = x;  out = xb;  base = blk; }
        else if (blk < 5632) { in = wa; out = wab; base = blk - 4096; }
        else                 { in = wp; out = wpb; base = blk - 5632; }
        int i = (base * 256 + threadIdx.x) << 3;
        float4 a = *(const float4*)(in + i);
        float4 b = *(const float4*)(in + i + 4);
        union { unsigned short u[8]; u32x4 v; } pk;
        pk.u[0] = f2bf(a.x); pk.u[1] = f2bf(a.y); pk.u[2] = f2bf(a.z); pk.u[3] = f2bf(a.w);
        pk.u[4] = f2bf(b.x); pk.u[5] = f2bf(b.y); pk.u[6] = f2bf(b.z); pk.u[7] = f2bf(b.w);
        *(u32x4*)(out + i) = pk.v;
    } else {
        int idx = (blk - 6144) * 256 + threadIdx.x;   // TSEQ * 32
        int t = idx >> 5;
        int i = idx & 31;
        double inv = pow(10000.0, -((double)(2 * i)) / (double)HDIM);
        double ph = (double)t * inv;
        cosT[idx] = (float)cos(ph);
        sinT[idx] = (float)sin(ph);
    }
}

// ============ bf16 MFMA GEMM core (C = A * B^T), 128x128 tile =================
// v5: LDS k-chunk swizzle (bank conflicts 6.29M -> 0 measured). Global source
// column pre-swizzled per lane (global_load_lds writes LDS linearly, rule #21);
// reads XOR the same key.
// v7: v6's triple-buffered counted-vmcnt pipeline, but with STATIC buffer
// addressing. v6's rotating cur/nxt (`if (nxt>=3) nxt-=3`) made every LDS base
// runtime-dynamic -> VALUBusy 16->36%, qkv 84->97us (regression). Here the
// 32-iteration K-loop is fully unrolled over the 3-buffer cycle (10x3 triples
// + 2 peeled), so all LDS offsets {0,4096,8192} are immediates. Counted
// s_waitcnt vmcnt(4) keeps tile t+1's loads in flight across the barrier
// (~1 iter of latency hiding); last iter drains vmcnt(0).
// WAR safety (validated by v6 passing): stage targets the buffer holding tile
// t-1, whose ds_reads finished pre-barrier (each wave drains lgkmcnt(0) before
// its s_barrier).
#define GROW(p) (((p) & 64) + (((p) & 15) << 2) + (((p) >> 4) & 3))
#define GEMM_STAGE(bufo, kofs)                                                   \
    do {                                                                         \
        __builtin_amdgcn_global_load_lds((gas_void*)(Ag0 + (kofs)), (las_void*)(Al0 + (bufo)), 16, 0, 0); \
        __builtin_amdgcn_global_load_lds((gas_void*)(Ag1 + (kofs)), (las_void*)(Al1 + (bufo)), 16, 0, 0); \
        __builtin_amdgcn_global_load_lds((gas_void*)(Bg0 + (kofs)), (las_void*)(Bl0 + (bufo)), 16, 0, 0); \
        __builtin_amdgcn_global_load_lds((gas_void*)(Bg1 + (kofs)), (las_void*)(Bl1 + (bufo)), 16, 0, 0); \
    } while (0)
#define GEMM_COMPUTE(bufo)                                                       \
    do {                                                                         \
        const unsigned short* Ab = As + (bufo);                                  \
        const unsigned short* Bb = Bs + (bufo);                                  \
        bf16x8 af[4], bf[4];                                                     \
        _Pragma("unroll")                                                        \
        for (int mi = 0; mi < 4; ++mi)                                           \
            af[mi] = __builtin_bit_cast(bf16x8,                                  \
                *(const u32x4*)(Ab + ((wm << 6) + (mi << 4) + l15) * 32 + ((quad ^ rsw) << 3))); \
        _Pragma("unroll")                                                        \
        for (int ni = 0; ni < 4; ++ni)                                           \
            bf[ni] = __builtin_bit_cast(bf16x8,                                  \
                *(const u32x4*)(Bb + ((wn << 6) + (ni << 4) + l15) * 32 + ((quad ^ rsw) << 3))); \
        _Pragma("unroll")                                                        \
        for (int mi = 0; mi < 4; ++mi)                                           \
            _Pragma("unroll")                                                    \
            for (int ni = 0; ni < 4; ++ni)                                       \
                acc[mi][ni] = __builtin_amdgcn_mfma_f32_16x16x32_bf16(af[mi], bf[ni], acc[mi][ni], 0, 0, 0); \
    } while (0)
#define GEMM_ITER(T, CO, NO)                                                     \
    do {                                                                         \
        if ((T) < 31) asm volatile("s_waitcnt vmcnt(4) lgkmcnt(0)\n\ts_barrier" ::: "memory"); \
        else          asm volatile("s_waitcnt vmcnt(0) lgkmcnt(0)\n\ts_barrier" ::: "memory"); \
        if ((T) + 2 < 32) GEMM_STAGE(NO, ((T) + 2) * 32);                        \
        GEMM_COMPUTE(CO);                                                        \
    } while (0)
// K_ must be 1024 (NT=32) for both call sites.
#define GEMM_CORE(A_, B_, K_, bm_, bn_)                                          \
    const int tid = threadIdx.x;                                                 \
    const int w = tid >> 6, lane = tid & 63;                                     \
    const int l15 = lane & 15, quad = lane >> 4;                                 \
    const int wm = w >> 1, wn = w & 1;                                           \
    const int srow = (w << 5) + (lane >> 2);                                     \
    const int kpart = (lane & 3) << 3;                                           \
    const int ksw = (((lane & 3) ^ ((lane >> 3) & 3)) << 3);                     \
    const int rsw = (l15 >> 1) & 3;                                              \
    const unsigned short* Ag0 = A_ + (size_t)(bm_ + srow) * K_ + ksw;            \
    const unsigned short* Ag1 = A_ + (size_t)(bm_ + srow + 16) * K_ + ksw;       \
    const unsigned short* Bg0 = B_ + (size_t)(bn_ + GROW(srow)) * K_ + ksw;      \
    const unsigned short* Bg1 = B_ + (size_t)(bn_ + GROW(srow + 16)) * K_ + ksw; \
    unsigned short* Al0 = As + srow * 32 + kpart;                                \
    unsigned short* Al1 = As + (srow + 16) * 32 + kpart;                         \
    unsigned short* Bl0 = Bs + srow * 32 + kpart;                                \
    unsigned short* Bl1 = Bs + (srow + 16) * 32 + kpart;                         \
    f32x4 acc[4][4];                                                             \
    _Pragma("unroll")                                                            \
    for (int i = 0; i < 4; ++i)                                                  \
        _Pragma("unroll")                                                        \
        for (int j = 0; j < 4; ++j) acc[i][j] = (f32x4){0.f, 0.f, 0.f, 0.f};     \
    {                                                                            \
        GEMM_STAGE(0, 0);                                                        \
        GEMM_STAGE(4096, 32);                                                    \
        _Pragma("unroll")                                                        \
        for (int t3 = 0; t3 < 30; t3 += 3) {                                     \
            GEMM_ITER(t3, 0, 8192);                                              \
            GEMM_ITER(t3 + 1, 4096, 0);                                          \
            GEMM_ITER(t3 + 2, 8192, 4096);                                       \
        }                                                                        \
        GEMM_ITER(30, 0, 8192);                                                  \
        GEMM_ITER(31, 4096, 0);                                                  \
    }

// ---------- QKV GEMM (M=8192, N=3072, K=1024) + fused RoPE/pack/V-transpose ---
__global__ __launch_bounds__(256) void gemm_qkv_fused(
        const unsigned short* __restrict__ A, const unsigned short* __restrict__ B,
        unsigned short* __restrict__ qb, unsigned short* __restrict__ kb,
        unsigned short* __restrict__ vb,
        const float* __restrict__ cosT, const float* __restrict__ sinT) {
    __shared__ __align__(16) unsigned short As[3 * 128 * 32];
    __shared__ __align__(16) unsigned short Bs[3 * 128 * 32];
    const int bm = blockIdx.y << 7;
    const int bn = blockIdx.x << 7;
    GEMM_CORE(A, B, CDIM, bm, bn)

    const int nbase = bn + (wn << 6);
    const int mbase = bm + (wm << 6);
    const int b = mbase >> 11;
    const int tt0 = mbase & (TSEQ - 1);
    const int d0 = l15 << 2;          // 4 consecutive d per thread
    const int fi = l15 << 1;          // freq index base = d0/2

    if (nbase < 2 * CDIM) {
        const int isQ = (nbase < CDIM) ? 1 : 0;
        unsigned short* dst = isQ ? qb : kb;
        const float qs = isQ ? 0.18033688f : 1.0f;   // 0.125 * log2(e)
        const int h = (nbase & (CDIM - 1)) >> 6;
        unsigned short* hb = dst + (size_t)(b * NHEAD + h) * TSEQ * HDIM;
#pragma unroll
        for (int mi = 0; mi < 4; ++mi) {
#pragma unroll
            for (int r = 0; r < 4; ++r) {
                const int t = tt0 + (mi << 4) + (quad << 2) + r;
                float2 cc = *(const float2*)(cosT + (t << 5) + fi);
                float2 ss = *(const float2*)(sinT + (t << 5) + fi);
                float re0 = acc[mi][0][r], im0 = acc[mi][1][r];
                float re1 = acc[mi][2][r], im1 = acc[mi][3][r];
                union { unsigned short u[4]; uint2 v; } pk;
                pk.u[0] = f2bf((re0 * cc.x - im0 * ss.x) * qs);
                pk.u[1] = f2bf((re0 * ss.x + im0 * cc.x) * qs);
                pk.u[2] = f2bf((re1 * cc.y - im1 * ss.y) * qs);
                pk.u[3] = f2bf((re1 * ss.y + im1 * cc.y) * qs);
                *(uint2*)(hb + (size_t)t * HDIM + d0) = pk.v;
            }
        }
    } else {
        const int h = (nbase - 2 * CDIM) >> 6;
        unsigned short* hb = vb + (size_t)(b * NHEAD + h) * HDIM * TSEQ;
#pragma unroll
        for (int mi = 0; mi < 4; ++mi) {
            const int t0 = tt0 + (mi << 4) + (quad << 2);
#pragma unroll
            for (int ni = 0; ni < 4; ++ni) {
                const int d = d0 + ni;
                union { unsigned short u[4]; uint2 v; } pk;
#pragma unroll
                for (int r = 0; r < 4; ++r) pk.u[r] = f2bf(acc[mi][ni][r]);
                *(uint2*)(hb + (size_t)d * TSEQ + t0) = pk.v;
            }
        }
    }
}

// ---------- proj GEMM (M=8192, N=1024, K=1024), fp32 output, float4 stores ----
__global__ __launch_bounds__(256) void gemm_proj(
        const unsigned short* __restrict__ A, const unsigned short* __restrict__ B,
        float* __restrict__ C) {
    __shared__ __align__(16) unsigned short As[3 * 128 * 32];
    __shared__ __align__(16) unsigned short Bs[3 * 128 * 32];
    const int bm = blockIdx.y << 7;
    const int bn = blockIdx.x << 7;
    GEMM_CORE(A, B, CDIM, bm, bn)

#pragma unroll
    for (int mi = 0; mi < 4; ++mi)
#pragma unroll
        for (int r = 0; r < 4; ++r) {
            const int row = bm + (wm << 6) + (mi << 4) + (quad << 2) + r;
            float4 v = make_float4(acc[mi][0][r], acc[mi][1][r], acc[mi][2][r], acc[mi][3][r]);
            *(float4*)(C + (size_t)row * CDIM + bn + (wn << 6) + (l15 << 2)) = v;
        }
}

// ---------------- Flash attention v4: swapped QK^T, zero-LDS softmax ----------
// S^T = mfma(A=K, B=Q): lane(l15,quad) gets S[q=ni*16+l15][key=16*mi+4*quad+r].
// The PV MFMA k-slot -> key mapping is chosen as pi(quad,j,kc)=16*(2kc+(j>>2))
// +4*quad+(j&3), so each lane's P A-fragment is PURELY LANE-LOCAL:
//   ap[ni][kc][j] = bf16(exp2(s[2kc+(j>>2)][ni][j&3]))   -- no LDS, no shuffle.
// V is staged with the matching column permutation col'=32*(m>>1)+8*q+4*(m&1)+r
// (key=16m+4q+r), so PV V-reads are single b128 with the proven chunk-XOR
// pattern. K staged with linear rows (sigma dropped; Ps gone).
// LDS: Ks[2]+Vs[2] = 32 KB (Ps' 32 KB freed). One barrier/kt (double buffer).
#define KTILE 64
#define NKT (TSEQ / KTILE)
#define QBLK 256
#define SWZ(row, ch) (((row) << 6) + ((((ch) ^ ((row) & 7))) << 3))
__global__ __launch_bounds__(256, 2) void attn_mfma(
        const unsigned short* __restrict__ qb, const unsigned short* __restrict__ kb,
        const unsigned short* __restrict__ vb, unsigned short* __restrict__ y) {
    const int bh = blockIdx.x;          // fast dim -> XCD L2 locality on K/V
    const int qt = blockIdx.y;
    const int b = bh >> 4, h = bh & 15;
    const int tid  = threadIdx.x;
    const int w    = tid >> 6;
    const int lane = tid & 63;
    const int l15  = lane & 15;
    const int quad = lane >> 4;

    __shared__ __align__(16) unsigned short Ks[2][KTILE * 64];
    __shared__ __align__(16) unsigned short Vs[2][HDIM * 64];

    // Q fragments (B-operand): aq[ni][kc] = Q[q=ni*16+l15][d=kc*32+quad*8+0..7]
    const size_t qoff = ((size_t)bh * TSEQ + qt * QBLK + w * 64) * HDIM;
    bf16x8 aq[4][2];
#pragma unroll
    for (int ni = 0; ni < 4; ++ni)
#pragma unroll
        for (int kc = 0; kc < 2; ++kc) {
            u32x4 v = *(const u32x4*)(qb + qoff + (size_t)(ni * 16 + l15) * HDIM + kc * 32 + quad * 8);
            aq[ni][kc] = __builtin_bit_cast(bf16x8, v);
        }

    f32x4 o[4][4];
    float l_r[4];   // partial row-sum for q=ni*16+l15 over this lane's (mi,r)
#pragma unroll
    for (int ni = 0; ni < 4; ++ni) {
        l_r[ni] = 0.f;
#pragma unroll
        for (int nc = 0; nc < 4; ++nc) o[ni][nc] = (f32x4){0.f, 0.f, 0.f, 0.f};
    }

    const unsigned short* kbase = kb + (size_t)bh * TSEQ * HDIM;
    const unsigned short* vbase = vb + (size_t)bh * HDIM * TSEQ;

    const int sr = tid >> 3;        // 0..31 (second element: +32)
    const int s8 = tid & 7;
    const int sp = s8 << 3;         // global col 0..56
    // K staging: linear rows sr / sr+32, col chunk s8
    const int stK0 = SWZ(sr, s8);
    const int stK1 = SWZ(sr + 32, s8);
    // V staging: sigma'd d-rows (row n holds true d=4*(n&15)+(n>>4)), permuted
    // key-cols col'=32*(m>>1)+8*q+4*(m&1)+r for key=16m+4q+r -> split b64 writes
    const int vrow0 = ((sr & 3) << 4) + (sr >> 2);
    const int vrow1 = vrow0 + 8;
    const int chV  = ((s8 >> 2) << 2) + ((s8 & 1) << 1);   // 4*(s>>2)+2*(s&1)
    const int offV = ((s8 >> 1) & 1) << 2;                 // 4*((s>>1)&1)
    const int e0 = vrow0 & 7;                              // == vrow1 & 7
    const int stV00 = (vrow0 << 6) + ((chV ^ e0) << 3) + offV;
    const int stV01 = (vrow0 << 6) + (((chV + 1) ^ e0) << 3) + offV;
    const int stV10 = (vrow1 << 6) + ((chV ^ e0) << 3) + offV;
    const int stV11 = (vrow1 << 6) + (((chV + 1) ^ e0) << 3) + offV;

    // prologue: tile 0 -> buf0; issue tile 1 loads
    u32x4 kr[2], vr[2];
#pragma unroll
    for (int l = 0; l < 2; ++l) {
        int idx = sr + (l << 5);
        kr[l] = *(const u32x4*)(kbase + (size_t)idx * HDIM + sp);
        vr[l] = *(const u32x4*)(vbase + (size_t)idx * TSEQ + sp);
    }
    *(u32x4*)&Ks[0][stK0] = kr[0];
    *(u32x4*)&Ks[0][stK1] = kr[1];
    *(uint2*)&Vs[0][stV00] = make_uint2(vr[0][0], vr[0][1]);
    *(uint2*)&Vs[0][stV01] = make_uint2(vr[0][2], vr[0][3]);
    *(uint2*)&Vs[0][stV10] = make_uint2(vr[1][0], vr[1][1]);
    *(uint2*)&Vs[0][stV11] = make_uint2(vr[1][2], vr[1][3]);
#pragma unroll
    for (int l = 0; l < 2; ++l) {
        int idx = sr + (l << 5);
        kr[l] = *(const u32x4*)(kbase + (size_t)(KTILE + idx) * HDIM + sp);
        vr[l] = *(const u32x4*)(vbase + (size_t)idx * TSEQ + KTILE + sp);
    }

    for (int kt = 0; kt < NKT; ++kt) {
        const int cur = kt & 1;
        __syncthreads();   // buf[cur] staged & visible; buf[cur^1] readers done

        // S^T = K Q (exp2 domain) + softmax + in-register P pack
        bf16x8 ap[4][2];
#pragma unroll
        for (int pvk = 0; pvk < 2; ++pvk) {
            f32x4 s[2][4];
#pragma unroll
            for (int mi2 = 0; mi2 < 2; ++mi2) {
                const int rowK = (pvk * 2 + mi2) * 16 + l15;
                bf16x8 k0 = __builtin_bit_cast(bf16x8, *(const u32x4*)&Ks[cur][SWZ(rowK, quad)]);
                bf16x8 k1 = __builtin_bit_cast(bf16x8, *(const u32x4*)&Ks[cur][SWZ(rowK, quad ^ 4)]);
#pragma unroll
                for (int ni = 0; ni < 4; ++ni) {
                    f32x4 a2 = (f32x4){0.f, 0.f, 0.f, 0.f};
                    a2 = __builtin_amdgcn_mfma_f32_16x16x32_bf16(k0, aq[ni][0], a2, 0, 0, 0);
                    a2 = __builtin_amdgcn_mfma_f32_16x16x32_bf16(k1, aq[ni][1], a2, 0, 0, 0);
                    s[mi2][ni] = a2;
                }
            }
#pragma unroll
            for (int ni = 0; ni < 4; ++ni) {
                float p0[4], p1[4];
#pragma unroll
                for (int r = 0; r < 4; ++r) {
                    p0[r] = __builtin_amdgcn_exp2f(s[0][ni][r]);
                    p1[r] = __builtin_amdgcn_exp2f(s[1][ni][r]);
                }
                l_r[ni] += ((p0[0] + p0[1]) + (p0[2] + p0[3]))
                         + ((p1[0] + p1[1]) + (p1[2] + p1[3]));
                u32x4 pk;
                pk[0] = __builtin_amdgcn_perm(__float_as_uint(p0[1]), __float_as_uint(p0[0]), 0x07060302u);
                pk[1] = __builtin_amdgcn_perm(__float_as_uint(p0[3]), __float_as_uint(p0[2]), 0x07060302u);
                pk[2] = __builtin_amdgcn_perm(__float_as_uint(p1[1]), __float_as_uint(p1[0]), 0x07060302u);
                pk[3] = __builtin_amdgcn_perm(__float_as_uint(p1[3]), __float_as_uint(p1[2]), 0x07060302u);
                ap[ni][pvk] = __builtin_bit_cast(bf16x8, pk);
            }
        }

        // stage next tile into buf^1; then issue tile kt+2 global loads
        if (kt + 1 < NKT) {
            const int nxt = cur ^ 1;
            *(u32x4*)&Ks[nxt][stK0] = kr[0];
            *(u32x4*)&Ks[nxt][stK1] = kr[1];
            *(uint2*)&Vs[nxt][stV00] = make_uint2(vr[0][0], vr[0][1]);
            *(uint2*)&Vs[nxt][stV01] = make_uint2(vr[0][2], vr[0][3]);
            *(uint2*)&Vs[nxt][stV10] = make_uint2(vr[1][0], vr[1][1]);
            *(uint2*)&Vs[nxt][stV11] = make_uint2(vr[1][2], vr[1][3]);
            if (kt + 2 < NKT) {
                int base = (kt + 2) * KTILE;
#pragma unroll
                for (int l = 0; l < 2; ++l) {
                    int idx = sr + (l << 5);
                    kr[l] = *(const u32x4*)(kbase + (size_t)(base + idx) * HDIM + sp);
                    vr[l] = *(const u32x4*)(vbase + (size_t)idx * TSEQ + base + sp);
                }
            }
        }

        // O += P V  (Vs col' order matches pi; d-rows sigma'd: col nc*16+l15 ->
        // true d=4*l15+nc)
#pragma unroll
        for (int nc = 0; nc < 4; ++nc) {
            const int rowV = nc * 16 + l15;
#pragma unroll
            for (int kc = 0; kc < 2; ++kc) {
                bf16x8 bv = __builtin_bit_cast(bf16x8,
                    *(const u32x4*)&Vs[cur][SWZ(rowV, (kc << 2) + quad)]);
#pragma unroll
                for (int ni = 0; ni < 4; ++ni)
                    o[ni][nc] = __builtin_amdgcn_mfma_f32_16x16x32_bf16(ap[ni][kc], bv, o[ni][nc], 0, 0, 0);
            }
        }
    }

    // l rowsum: reduce across the 4 quads (key dim spans quads now)
#pragma unroll
    for (int ni = 0; ni < 4; ++ni) {
        l_r[ni] += __shfl_xor(l_r[ni], 16, 64);
        l_r[ni] += __shfl_xor(l_r[ni], 32, 64);
    }
    // redistribute: o-row q=ni*16+quad*4+r needs l held at lanes l15=quad*4+r
    const int srcl = (quad << 4) + (quad << 2);
#pragma unroll
    for (int ni = 0; ni < 4; ++ni)
#pragma unroll
        for (int r = 0; r < 4; ++r) {
            float inv_l = 1.f / __shfl(l_r[ni], srcl + r, 64);
            int t = qt * QBLK + w * 64 + ni * 16 + quad * 4 + r;
            unsigned short* row = y + (size_t)(b * TSEQ + t) * CDIM + h * HDIM;
            union { unsigned short u[4]; uint2 v; } pk;
#pragma unroll
            for (int nc = 0; nc < 4; ++nc) pk.u[nc] = f2bf(o[ni][nc][r] * inv_l);
            *(uint2*)(row + (l15 << 2)) = pk.v;
        }
}

extern "C" void kernel_launch(void* const* d_in, const int* in_sizes, int n_in,
                              void* d_out, int out_size, void* d_ws, size_t ws_size,
                              hipStream_t stream) {
    const float* x      = (const float*)d_in[0];
    const float* w_attn = (const float*)d_in[1];
    const float* w_proj = (const float*)d_in[2];
    float* out = (float*)d_out;

    unsigned short* xb  = (unsigned short*)d_ws;
    unsigned short* wab = xb  + (size_t)M_ROWS * CDIM;
    unsigned short* wpb = wab + (size_t)3 * CDIM * CDIM;
    unsigned short* qb  = wpb + (size_t)CDIM * CDIM;
    unsigned short* kb  = qb  + (size_t)BATCH * NHEAD * TSEQ * HDIM;
    unsigned short* vb  = kb  + (size_t)BATCH * NHEAD * TSEQ * HDIM;
    unsigned short* yb  = vb  + (size_t)BATCH * NHEAD * TSEQ * HDIM;
    float* cosT = (float*)(yb + (size_t)M_ROWS * CDIM);
    float* sinT = cosT + TSEQ * (HDIM / 2);

    prep_kernel<<<6400, 256, 0, stream>>>(x, xb, w_attn, wab, w_proj, wpb, cosT, sinT);

    dim3 g1(3 * CDIM / 128, M_ROWS / 128);
    gemm_qkv_fused<<<g1, 256, 0, stream>>>(xb, wab, qb, kb, vb, cosT, sinT);

    dim3 g2(BATCH * NHEAD, TSEQ / QBLK);
    attn_mfma<<<g2, 256, 0, stream>>>(qb, kb, vb, yb);

    dim3 g3(CDIM / 128, M_ROWS / 128);
    gemm_proj<<<g3, 256, 0, stream>>>(yb, wpb, out);
}

// Round 8
// 254.748 us; speedup vs baseline: 1.0824x; 1.0824x over previous
//
#include <hip/hip_runtime.h>
#include <math.h>

#define BATCH 4
#define TSEQ 2048
#define CDIM 1024
#define NHEAD 16
#define HDIM 64
#define M_ROWS (BATCH * TSEQ)   // 8192

typedef float f32x4 __attribute__((ext_vector_type(4)));
typedef __bf16 bf16x8 __attribute__((ext_vector_type(8)));
typedef unsigned int u32x4 __attribute__((ext_vector_type(4)));

typedef const __attribute__((address_space(1))) void gas_void;
typedef __attribute__((address_space(3))) void las_void;

static __device__ __forceinline__ unsigned short f2bf(float f) {
    unsigned int x = __float_as_uint(f);
    x += 0x7fffu + ((x >> 16) & 1u);
    return (unsigned short)(x >> 16);
}

// ---------------- merged prep: 3x fp32->bf16 cvt + RoPE table -----------------
// block ranges: [0,4096) x, [4096,5632) w_attn, [5632,6144) w_proj, [6144,6400) rope
__global__ void prep_kernel(const float* __restrict__ x, unsigned short* __restrict__ xb,
                            const float* __restrict__ wa, unsigned short* __restrict__ wab,
                            const float* __restrict__ wp, unsigned short* __restrict__ wpb,
                            float* __restrict__ cosT, float* __restrict__ sinT) {
    int blk = blockIdx.x;
    if (blk < 6144) {
        const float* in;
        unsigned short* out;
        int base;
        if (blk < 4096)      { in = x;  out = xb;  base = blk; }
        else if (blk < 5632) { in = wa; out = wab; base = blk - 4096; }
        else                 { in = wp; out = wpb; base = blk - 5632; }
        int i = (base * 256 + threadIdx.x) << 3;
        float4 a = *(const float4*)(in + i);
        float4 b = *(const float4*)(in + i + 4);
        union { unsigned short u[8]; u32x4 v; } pk;
        pk.u[0] = f2bf(a.x); pk.u[1] = f2bf(a.y); pk.u[2] = f2bf(a.z); pk.u[3] = f2bf(a.w);
        pk.u[4] = f2bf(b.x); pk.u[5] = f2bf(b.y); pk.u[6] = f2bf(b.z); pk.u[7] = f2bf(b.w);
        *(u32x4*)(out + i) = pk.v;
    } else {
        int idx = (blk - 6144) * 256 + threadIdx.x;   // TSEQ * 32
        int t = idx >> 5;
        int i = idx & 31;
        double inv = pow(10000.0, -((double)(2 * i)) / (double)HDIM);
        double ph = (double)t * inv;
        cosT[idx] = (float)cos(ph);
        sinT[idx] = (float)sin(ph);
    }
}

// ============ bf16 MFMA GEMM core (C = A * B^T), 128x128 tile, BK=64 ==========
// v5: LDS chunk swizzle -> conflict-free fragment reads (6.29M -> 0 measured).
// v8: REVERT of the v6/v7 counted-vmcnt pipeline (r6 96.6us / r7 90.1us, both
// worse than v5's 83.7 -> replicates the guide's regime gate: T4 counted-vmcnt
// is null at 2-phase 128²). Back to the simple __syncthreads loop, but with
// BK=64: one 128x64 tile staged per barrier pair (8 global_load_lds/wave,
// 32 KB LDS single-buffered) -> 16 vmcnt(0) drain events per block instead of
// 32, and 8 outstanding loads per drain (vs 4). MFMA/ds_read per K unchanged.
// Swizzle at 128B rows: LDS slot (row,cpos) holds global k-chunk cpos^(row&7);
// stage ksw = ((lane&7)^((lane>>3)&7))*8; read cpos = (kk*4+quad)^(l15&7).
// 8 distinct 16B slots x 2 lanes = 2-way = free.
#define GROW(p) (((p) & 64) + (((p) & 15) << 2) + (((p) >> 4) & 3))
#define GEMM_CORE(A_, B_, K_, bm_, bn_)                                          \
    const int tid = threadIdx.x;                                                 \
    const int w = tid >> 6, lane = tid & 63;                                     \
    const int l15 = lane & 15, quad = lane >> 4;                                 \
    const int wm = w >> 1, wn = w & 1;                                           \
    const int ksw = ((lane & 7) ^ ((lane >> 3) & 7)) << 3;                       \
    const int rx = l15 & 7;                                                      \
    const unsigned short* Ag[4]; const unsigned short* Bg[4];                    \
    unsigned short* Al[4]; unsigned short* Bl[4];                                \
    _Pragma("unroll")                                                            \
    for (int i = 0; i < 4; ++i) {                                                \
        const int row = (w << 5) + (i << 3) + (lane >> 3);                       \
        Ag[i] = A_ + (size_t)(bm_ + row) * K_ + ksw;                             \
        Bg[i] = B_ + (size_t)(bn_ + GROW(row)) * K_ + ksw;                       \
        Al[i] = As + row * 64 + ((lane & 7) << 3);                               \
        Bl[i] = Bs + row * 64 + ((lane & 7) << 3);                               \
    }                                                                            \
    f32x4 acc[4][4];                                                             \
    _Pragma("unroll")                                                            \
    for (int i = 0; i < 4; ++i)                                                  \
        _Pragma("unroll")                                                        \
        for (int j = 0; j < 4; ++j) acc[i][j] = (f32x4){0.f, 0.f, 0.f, 0.f};     \
    for (int t = 0; t < K_ / 64; ++t) {                                          \
        _Pragma("unroll")                                                        \
        for (int i = 0; i < 4; ++i) {                                            \
            __builtin_amdgcn_global_load_lds((gas_void*)(Ag[i] + t * 64), (las_void*)Al[i], 16, 0, 0); \
            __builtin_amdgcn_global_load_lds((gas_void*)(Bg[i] + t * 64), (las_void*)Bl[i], 16, 0, 0); \
        }                                                                        \
        __syncthreads();                                                         \
        _Pragma("unroll")                                                        \
        for (int kk = 0; kk < 2; ++kk) {                                         \
            bf16x8 af[4], bf[4];                                                 \
            _Pragma("unroll")                                                    \
            for (int mi = 0; mi < 4; ++mi)                                       \
                af[mi] = __builtin_bit_cast(bf16x8,                              \
                    *(const u32x4*)(As + ((wm << 6) + (mi << 4) + l15) * 64 + ((((kk << 2) + quad) ^ rx) << 3))); \
            _Pragma("unroll")                                                    \
            for (int ni = 0; ni < 4; ++ni)                                       \
                bf[ni] = __builtin_bit_cast(bf16x8,                              \
                    *(const u32x4*)(Bs + ((wn << 6) + (ni << 4) + l15) * 64 + ((((kk << 2) + quad) ^ rx) << 3))); \
            _Pragma("unroll")                                                    \
            for (int mi = 0; mi < 4; ++mi)                                       \
                _Pragma("unroll")                                                \
                for (int ni = 0; ni < 4; ++ni)                                   \
                    acc[mi][ni] = __builtin_amdgcn_mfma_f32_16x16x32_bf16(af[mi], bf[ni], acc[mi][ni], 0, 0, 0); \
        }                                                                        \
        __syncthreads();                                                         \
    }

// ---------- QKV GEMM (M=8192, N=3072, K=1024) + fused RoPE/pack/V-transpose ---
__global__ __launch_bounds__(256) void gemm_qkv_fused(
        const unsigned short* __restrict__ A, const unsigned short* __restrict__ B,
        unsigned short* __restrict__ qb, unsigned short* __restrict__ kb,
        unsigned short* __restrict__ vb,
        const float* __restrict__ cosT, const float* __restrict__ sinT) {
    __shared__ __align__(16) unsigned short As[128 * 64];
    __shared__ __align__(16) unsigned short Bs[128 * 64];
    const int bm = blockIdx.y << 7;
    const int bn = blockIdx.x << 7;
    GEMM_CORE(A, B, CDIM, bm, bn)

    const int nbase = bn + (wn << 6);
    const int mbase = bm + (wm << 6);
    const int b = mbase >> 11;
    const int tt0 = mbase & (TSEQ - 1);
    const int d0 = l15 << 2;          // 4 consecutive d per thread
    const int fi = l15 << 1;          // freq index base = d0/2

    if (nbase < 2 * CDIM) {
        const int isQ = (nbase < CDIM) ? 1 : 0;
        unsigned short* dst = isQ ? qb : kb;
        const float qs = isQ ? 0.18033688f : 1.0f;   // 0.125 * log2(e)
        const int h = (nbase & (CDIM - 1)) >> 6;
        unsigned short* hb = dst + (size_t)(b * NHEAD + h) * TSEQ * HDIM;
#pragma unroll
        for (int mi = 0; mi < 4; ++mi) {
#pragma unroll
            for (int r = 0; r < 4; ++r) {
                const int t = tt0 + (mi << 4) + (quad << 2) + r;
                float2 cc = *(const float2*)(cosT + (t << 5) + fi);
                float2 ss = *(const float2*)(sinT + (t << 5) + fi);
                float re0 = acc[mi][0][r], im0 = acc[mi][1][r];
                float re1 = acc[mi][2][r], im1 = acc[mi][3][r];
                union { unsigned short u[4]; uint2 v; } pk;
                pk.u[0] = f2bf((re0 * cc.x - im0 * ss.x) * qs);
                pk.u[1] = f2bf((re0 * ss.x + im0 * cc.x) * qs);
                pk.u[2] = f2bf((re1 * cc.y - im1 * ss.y) * qs);
                pk.u[3] = f2bf((re1 * ss.y + im1 * cc.y) * qs);
                *(uint2*)(hb + (size_t)t * HDIM + d0) = pk.v;
            }
        }
    } else {
        const int h = (nbase - 2 * CDIM) >> 6;
        unsigned short* hb = vb + (size_t)(b * NHEAD + h) * HDIM * TSEQ;
#pragma unroll
        for (int mi = 0; mi < 4; ++mi) {
            const int t0 = tt0 + (mi << 4) + (quad << 2);
#pragma unroll
            for (int ni = 0; ni < 4; ++ni) {
                const int d = d0 + ni;
                union { unsigned short u[4]; uint2 v; } pk;
#pragma unroll
                for (int r = 0; r < 4; ++r) pk.u[r] = f2bf(acc[mi][ni][r]);
                *(uint2*)(hb + (size_t)d * TSEQ + t0) = pk.v;
            }
        }
    }
}

// ---------- proj GEMM (M=8192, N=1024, K=1024), fp32 output, float4 stores ----
__global__ __launch_bounds__(256) void gemm_proj(
        const unsigned short* __restrict__ A, const unsigned short* __restrict__ B,
        float* __restrict__ C) {
    __shared__ __align__(16) unsigned short As[128 * 64];
    __shared__ __align__(16) unsigned short Bs[128 * 64];
    const int bm = blockIdx.y << 7;
    const int bn = blockIdx.x << 7;
    GEMM_CORE(A, B, CDIM, bm, bn)

#pragma unroll
    for (int mi = 0; mi < 4; ++mi)
#pragma unroll
        for (int r = 0; r < 4; ++r) {
            const int row = bm + (wm << 6) + (mi << 4) + (quad << 2) + r;
            float4 v = make_float4(acc[mi][0][r], acc[mi][1][r], acc[mi][2][r], acc[mi][3][r]);
            *(float4*)(C + (size_t)row * CDIM + bn + (wn << 6) + (l15 << 2)) = v;
        }
}

// ---------------- Flash attention v4: swapped QK^T, zero-LDS softmax ----------
// S^T = mfma(A=K, B=Q): lane(l15,quad) gets S[q=ni*16+l15][key=16*mi+4*quad+r].
// The PV MFMA k-slot -> key mapping is chosen as pi(quad,j,kc)=16*(2kc+(j>>2))
// +4*quad+(j&3), so each lane's P A-fragment is PURELY LANE-LOCAL:
//   ap[ni][kc][j] = bf16(exp2(s[2kc+(j>>2)][ni][j&3]))   -- no LDS, no shuffle.
// V is staged with the matching column permutation col'=32*(m>>1)+8*q+4*(m&1)+r
// (key=16m+4q+r), so PV V-reads are single b128 with the proven chunk-XOR
// pattern. K staged with linear rows (sigma dropped; Ps gone).
// LDS: Ks[2]+Vs[2] = 32 KB (Ps' 32 KB freed). One barrier/kt (double buffer).
#define KTILE 64
#define NKT (TSEQ / KTILE)
#define QBLK 256
#define SWZ(row, ch) (((row) << 6) + ((((ch) ^ ((row) & 7))) << 3))
__global__ __launch_bounds__(256, 2) void attn_mfma(
        const unsigned short* __restrict__ qb, const unsigned short* __restrict__ kb,
        const unsigned short* __restrict__ vb, unsigned short* __restrict__ y) {
    const int bh = blockIdx.x;          // fast dim -> XCD L2 locality on K/V
    const int qt = blockIdx.y;
    const int b = bh >> 4, h = bh & 15;
    const int tid  = threadIdx.x;
    const int w    = tid >> 6;
    const int lane = tid & 63;
    const int l15  = lane & 15;
    const int quad = lane >> 4;

    __shared__ __align__(16) unsigned short Ks[2][KTILE * 64];
    __shared__ __align__(16) unsigned short Vs[2][HDIM * 64];

    // Q fragments (B-operand): aq[ni][kc] = Q[q=ni*16+l15][d=kc*32+quad*8+0..7]
    const size_t qoff = ((size_t)bh * TSEQ + qt * QBLK + w * 64) * HDIM;
    bf16x8 aq[4][2];
#pragma unroll
    for (int ni = 0; ni < 4; ++ni)
#pragma unroll
        for (int kc = 0; kc < 2; ++kc) {
            u32x4 v = *(const u32x4*)(qb + qoff + (size_t)(ni * 16 + l15) * HDIM + kc * 32 + quad * 8);
            aq[ni][kc] = __builtin_bit_cast(bf16x8, v);
        }

    f32x4 o[4][4];
    float l_r[4];   // partial row-sum for q=ni*16+l15 over this lane's (mi,r)
#pragma unroll
    for (int ni = 0; ni < 4; ++ni) {
        l_r[ni] = 0.f;
#pragma unroll
        for (int nc = 0; nc < 4; ++nc) o[ni][nc] = (f32x4){0.f, 0.f, 0.f, 0.f};
    }

    const unsigned short* kbase = kb + (size_t)bh * TSEQ * HDIM;
    const unsigned short* vbase = vb + (size_t)bh * HDIM * TSEQ;

    const int sr = tid >> 3;        // 0..31 (second element: +32)
    const int s8 = tid & 7;
    const int sp = s8 << 3;         // global col 0..56
    // K staging: linear rows sr / sr+32, col chunk s8
    const int stK0 = SWZ(sr, s8);
    const int stK1 = SWZ(sr + 32, s8);
    // V staging: sigma'd d-rows (row n holds true d=4*(n&15)+(n>>4)), permuted
    // key-cols col'=32*(m>>1)+8*q+4*(m&1)+r for key=16m+4q+r -> split b64 writes
    const int vrow0 = ((sr & 3) << 4) + (sr >> 2);
    const int vrow1 = vrow0 + 8;
    const int chV  = ((s8 >> 2) << 2) + ((s8 & 1) << 1);   // 4*(s>>2)+2*(s&1)
    const int offV = ((s8 >> 1) & 1) << 2;                 // 4*((s>>1)&1)
    const int e0 = vrow0 & 7;                              // == vrow1 & 7
    const int stV00 = (vrow0 << 6) + ((chV ^ e0) << 3) + offV;
    const int stV01 = (vrow0 << 6) + (((chV + 1) ^ e0) << 3) + offV;
    const int stV10 = (vrow1 << 6) + ((chV ^ e0) << 3) + offV;
    const int stV11 = (vrow1 << 6) + (((chV + 1) ^ e0) << 3) + offV;

    // prologue: tile 0 -> buf0; issue tile 1 loads
    u32x4 kr[2], vr[2];
#pragma unroll
    for (int l = 0; l < 2; ++l) {
        int idx = sr + (l << 5);
        kr[l] = *(const u32x4*)(kbase + (size_t)idx * HDIM + sp);
        vr[l] = *(const u32x4*)(vbase + (size_t)idx * TSEQ + sp);
    }
    *(u32x4*)&Ks[0][stK0] = kr[0];
    *(u32x4*)&Ks[0][stK1] = kr[1];
    *(uint2*)&Vs[0][stV00] = make_uint2(vr[0][0], vr[0][1]);
    *(uint2*)&Vs[0][stV01] = make_uint2(vr[0][2], vr[0][3]);
    *(uint2*)&Vs[0][stV10] = make_uint2(vr[1][0], vr[1][1]);
    *(uint2*)&Vs[0][stV11] = make_uint2(vr[1][2], vr[1][3]);
#pragma unroll
    for (int l = 0; l < 2; ++l) {
        int idx = sr + (l << 5);
        kr[l] = *(const u32x4*)(kbase + (size_t)(KTILE + idx) * HDIM + sp);
        vr[l] = *(const u32x4*)(vbase + (size_t)idx * TSEQ + KTILE + sp);
    }

    for (int kt = 0; kt < NKT; ++kt) {
        const int cur = kt & 1;
        __syncthreads();   // buf[cur] staged & visible; buf[cur^1] readers done

        // S^T = K Q (exp2 domain) + softmax + in-register P pack
        bf16x8 ap[4][2];
#pragma unroll
        for (int pvk = 0; pvk < 2; ++pvk) {
            f32x4 s[2][4];
#pragma unroll
            for (int mi2 = 0; mi2 < 2; ++mi2) {
                const int rowK = (pvk * 2 + mi2) * 16 + l15;
                bf16x8 k0 = __builtin_bit_cast(bf16x8, *(const u32x4*)&Ks[cur][SWZ(rowK, quad)]);
                bf16x8 k1 = __builtin_bit_cast(bf16x8, *(const u32x4*)&Ks[cur][SWZ(rowK, quad ^ 4)]);
#pragma unroll
                for (int ni = 0; ni < 4; ++ni) {
                    f32x4 a2 = (f32x4){0.f, 0.f, 0.f, 0.f};
                    a2 = __builtin_amdgcn_mfma_f32_16x16x32_bf16(k0, aq[ni][0], a2, 0, 0, 0);
                    a2 = __builtin_amdgcn_mfma_f32_16x16x32_bf16(k1, aq[ni][1], a2, 0, 0, 0);
                    s[mi2][ni] = a2;
                }
            }
#pragma unroll
            for (int ni = 0; ni < 4; ++ni) {
                float p0[4], p1[4];
#pragma unroll
                for (int r = 0; r < 4; ++r) {
                    p0[r] = __builtin_amdgcn_exp2f(s[0][ni][r]);
                    p1[r] = __builtin_amdgcn_exp2f(s[1][ni][r]);
                }
                l_r[ni] += ((p0[0] + p0[1]) + (p0[2] + p0[3]))
                         + ((p1[0] + p1[1]) + (p1[2] + p1[3]));
                u32x4 pk;
                pk[0] = __builtin_amdgcn_perm(__float_as_uint(p0[1]), __float_as_uint(p0[0]), 0x07060302u);
                pk[1] = __builtin_amdgcn_perm(__float_as_uint(p0[3]), __float_as_uint(p0[2]), 0x07060302u);
                pk[2] = __builtin_amdgcn_perm(__float_as_uint(p1[1]), __float_as_uint(p1[0]), 0x07060302u);
                pk[3] = __builtin_amdgcn_perm(__float_as_uint(p1[3]), __float_as_uint(p1[2]), 0x07060302u);
                ap[ni][pvk] = __builtin_bit_cast(bf16x8, pk);
            }
        }

        // stage next tile into buf^1; then issue tile kt+2 global loads
        if (kt + 1 < NKT) {
            const int nxt = cur ^ 1;
            *(u32x4*)&Ks[nxt][stK0] = kr[0];
            *(u32x4*)&Ks[nxt][stK1] = kr[1];
            *(uint2*)&Vs[nxt][stV00] = make_uint2(vr[0][0], vr[0][1]);
            *(uint2*)&Vs[nxt][stV01] = make_uint2(vr[0][2], vr[0][3]);
            *(uint2*)&Vs[nxt][stV10] = make_uint2(vr[1][0], vr[1][1]);
            *(uint2*)&Vs[nxt][stV11] = make_uint2(vr[1][2], vr[1][3]);
            if (kt + 2 < NKT) {
                int base = (kt + 2) * KTILE;
#pragma unroll
                for (int l = 0; l < 2; ++l) {
                    int idx = sr + (l << 5);
                    kr[l] = *(const u32x4*)(kbase + (size_t)(base + idx) * HDIM + sp);
                    vr[l] = *(const u32x4*)(vbase + (size_t)idx * TSEQ + base + sp);
                }
            }
        }

        // O += P V  (Vs col' order matches pi; d-rows sigma'd: col nc*16+l15 ->
        // true d=4*l15+nc)
#pragma unroll
        for (int nc = 0; nc < 4; ++nc) {
            const int rowV = nc * 16 + l15;
#pragma unroll
            for (int kc = 0; kc < 2; ++kc) {
                bf16x8 bv = __builtin_bit_cast(bf16x8,
                    *(const u32x4*)&Vs[cur][SWZ(rowV, (kc << 2) + quad)]);
#pragma unroll
                for (int ni = 0; ni < 4; ++ni)
                    o[ni][nc] = __builtin_amdgcn_mfma_f32_16x16x32_bf16(ap[ni][kc], bv, o[ni][nc], 0, 0, 0);
            }
        }
    }

    // l rowsum: reduce across the 4 quads (key dim spans quads now)
#pragma unroll
    for (int ni = 0; ni < 4; ++ni) {
        l_r[ni] += __shfl_xor(l_r[ni], 16, 64);
        l_r[ni] += __shfl_xor(l_r[ni], 32, 64);
    }
    // redistribute: o-row q=ni*16+quad*4+r needs l held at lanes l15=quad*4+r
    const int srcl = (quad << 4) + (quad << 2);
#pragma unroll
    for (int ni = 0; ni < 4; ++ni)
#pragma unroll
        for (int r = 0; r < 4; ++r) {
            float inv_l = 1.f / __shfl(l_r[ni], srcl + r, 64);
            int t = qt * QBLK + w * 64 + ni * 16 + quad * 4 + r;
            unsigned short* row = y + (size_t)(b * TSEQ + t) * CDIM + h * HDIM;
            union { unsigned short u[4]; uint2 v; } pk;
#pragma unroll
            for (int nc = 0; nc < 4; ++nc) pk.u[nc] = f2bf(o[ni][nc][r] * inv_l);
            *(uint2*)(row + (l15 << 2)) = pk.v;
        }
}

extern "C" void kernel_launch(void* const* d_in, const int* in_sizes, int n_in,
                              void* d_out, int out_size, void* d_ws, size_t ws_size,
                              hipStream_t stream) {
    const float* x      = (const float*)d_in[0];
    const float* w_attn = (const float*)d_in[1];
    const float* w_proj = (const float*)d_in[2];
    float* out = (float*)d_out;

    unsigned short* xb  = (unsigned short*)d_ws;
    unsigned short* wab = xb  + (size_t)M_ROWS * CDIM;
    unsigned short* wpb = wab + (size_t)3 * CDIM * CDIM;
    unsigned short* qb  = wpb + (size_t)CDIM * CDIM;
    unsigned short* kb  = qb  + (size_t)BATCH * NHEAD * TSEQ * HDIM;
    unsigned short* vb  = kb  + (size_t)BATCH * NHEAD * TSEQ * HDIM;
    unsigned short* yb  = vb  + (size_t)BATCH * NHEAD * TSEQ * HDIM;
    float* cosT = (float*)(yb + (size_t)M_ROWS * CDIM);
    float* sinT = cosT + TSEQ * (HDIM / 2);

    prep_kernel<<<6400, 256, 0, stream>>>(x, xb, w_attn, wab, w_proj, wpb, cosT, sinT);

    dim3 g1(3 * CDIM / 128, M_ROWS / 128);
    gemm_qkv_fused<<<g1, 256, 0, stream>>>(xb, wab, qb, kb, vb, cosT, sinT);

    dim3 g2(BATCH * NHEAD, TSEQ / QBLK);
    attn_mfma<<<g2, 256, 0, stream>>>(qb, kb, vb, yb);

    dim3 g3(CDIM / 128, M_ROWS / 128);
    gemm_proj<<<g3, 256, 0, stream>>>(yb, wpb, out);
}

// Round 9
// 242.228 us; speedup vs baseline: 1.1383x; 1.0517x over previous
//
#include <hip/hip_runtime.h>
#include <math.h>

#define BATCH 4
#define TSEQ 2048
#define CDIM 1024
#define NHEAD 16
#define HDIM 64
#define M_ROWS (BATCH * TSEQ)   // 8192

typedef float f32x4 __attribute__((ext_vector_type(4)));
typedef __bf16 bf16x8 __attribute__((ext_vector_type(8)));
typedef unsigned int u32x4 __attribute__((ext_vector_type(4)));

typedef const __attribute__((address_space(1))) void gas_void;
typedef __attribute__((address_space(3))) void las_void;

static __device__ __forceinline__ unsigned short f2bf(float f) {
    unsigned int x = __float_as_uint(f);
    x += 0x7fffu + ((x >> 16) & 1u);
    return (unsigned short)(x >> 16);
}

// ---------------- merged prep: 3x fp32->bf16 cvt + RoPE table -----------------
// block ranges: [0,4096) x, [4096,5632) w_attn, [5632,6144) w_proj, [6144,6400) rope
__global__ void prep_kernel(const float* __restrict__ x, unsigned short* __restrict__ xb,
                            const float* __restrict__ wa, unsigned short* __restrict__ wab,
                            const float* __restrict__ wp, unsigned short* __restrict__ wpb,
                            float* __restrict__ cosT, float* __restrict__ sinT) {
    int blk = blockIdx.x;
    if (blk < 6144) {
        const float* in;
        unsigned short* out;
        int base;
        if (blk < 4096)      { in = x;  out = xb;  base = blk; }
        else if (blk < 5632) { in = wa; out = wab; base = blk - 4096; }
        else                 { in = wp; out = wpb; base = blk - 5632; }
        int i = (base * 256 + threadIdx.x) << 3;
        float4 a = *(const float4*)(in + i);
        float4 b = *(const float4*)(in + i + 4);
        union { unsigned short u[8]; u32x4 v; } pk;
        pk.u[0] = f2bf(a.x); pk.u[1] = f2bf(a.y); pk.u[2] = f2bf(a.z); pk.u[3] = f2bf(a.w);
        pk.u[4] = f2bf(b.x); pk.u[5] = f2bf(b.y); pk.u[6] = f2bf(b.z); pk.u[7] = f2bf(b.w);
        *(u32x4*)(out + i) = pk.v;
    } else {
        int idx = (blk - 6144) * 256 + threadIdx.x;   // TSEQ * 32
        int t = idx >> 5;
        int i = idx & 31;
        double inv = pow(10000.0, -((double)(2 * i)) / (double)HDIM);
        double ph = (double)t * inv;
        cosT[idx] = (float)cos(ph);
        sinT[idx] = (float)sin(ph);
    }
}

// ============ bf16 MFMA GEMM core (C = A * B^T), 128x128 tile, BK=64 ==========
// v5: LDS chunk swizzle -> conflict-free fragment reads (6.29M -> 0 measured).
// v8: simple 2-barrier loop with BK=64 (16 drain events, 8 loads each) --
//     measured 83.7 -> 78.2us; counted-vmcnt pipelines (v6/v7) both regressed,
//     replicating the T4-at-2-phase regime gate.
// v9: (a) t-loop FULLY UNROLLED: global_load_lds addresses fold into the
//     13-bit offset immediate (t*128B <= 1920) and fragment addresses become
//     loop-invariant -> kills the per-iter 64-bit pointer VALU that pushed
//     VALUBusy 16->37.6% in v8's rolled loop.
//     (b) callers apply bijective XCD swizzle (T1): each XCD gets 8 contiguous
//     row-bands -> each A-panel fetched by ONE XCD's L2 (FETCH 83MB ~= 8x A
//     re-fetch today).
#define GROW(p) (((p) & 64) + (((p) & 15) << 2) + (((p) >> 4) & 3))
#define GEMM_CORE(A_, B_, K_, bm_, bn_)                                          \
    const int tid = threadIdx.x;                                                 \
    const int w = tid >> 6, lane = tid & 63;                                     \
    const int l15 = lane & 15, quad = lane >> 4;                                 \
    const int wm = w >> 1, wn = w & 1;                                           \
    const int ksw = ((lane & 7) ^ ((lane >> 3) & 7)) << 3;                       \
    const int rx = l15 & 7;                                                      \
    const unsigned short* Ag[4]; const unsigned short* Bg[4];                    \
    unsigned short* Al[4]; unsigned short* Bl[4];                                \
    _Pragma("unroll")                                                            \
    for (int i = 0; i < 4; ++i) {                                                \
        const int row = (w << 5) + (i << 3) + (lane >> 3);                       \
        Ag[i] = A_ + (size_t)(bm_ + row) * K_ + ksw;                             \
        Bg[i] = B_ + (size_t)(bn_ + GROW(row)) * K_ + ksw;                       \
        Al[i] = As + row * 64 + ((lane & 7) << 3);                               \
        Bl[i] = Bs + row * 64 + ((lane & 7) << 3);                               \
    }                                                                            \
    f32x4 acc[4][4];                                                             \
    _Pragma("unroll")                                                            \
    for (int i = 0; i < 4; ++i)                                                  \
        _Pragma("unroll")                                                        \
        for (int j = 0; j < 4; ++j) acc[i][j] = (f32x4){0.f, 0.f, 0.f, 0.f};     \
    _Pragma("unroll")                                                            \
    for (int t = 0; t < K_ / 64; ++t) {                                          \
        _Pragma("unroll")                                                        \
        for (int i = 0; i < 4; ++i) {                                            \
            __builtin_amdgcn_global_load_lds((gas_void*)(Ag[i] + t * 64), (las_void*)Al[i], 16, 0, 0); \
            __builtin_amdgcn_global_load_lds((gas_void*)(Bg[i] + t * 64), (las_void*)Bl[i], 16, 0, 0); \
        }                                                                        \
        __syncthreads();                                                         \
        _Pragma("unroll")                                                        \
        for (int kk = 0; kk < 2; ++kk) {                                         \
            bf16x8 af[4], bf[4];                                                 \
            _Pragma("unroll")                                                    \
            for (int mi = 0; mi < 4; ++mi)                                       \
                af[mi] = __builtin_bit_cast(bf16x8,                              \
                    *(const u32x4*)(As + ((wm << 6) + (mi << 4) + l15) * 64 + ((((kk << 2) + quad) ^ rx) << 3))); \
            _Pragma("unroll")                                                    \
            for (int ni = 0; ni < 4; ++ni)                                       \
                bf[ni] = __builtin_bit_cast(bf16x8,                              \
                    *(const u32x4*)(Bs + ((wn << 6) + (ni << 4) + l15) * 64 + ((((kk << 2) + quad) ^ rx) << 3))); \
            _Pragma("unroll")                                                    \
            for (int mi = 0; mi < 4; ++mi)                                       \
                _Pragma("unroll")                                                \
                for (int ni = 0; ni < 4; ++ni)                                   \
                    acc[mi][ni] = __builtin_amdgcn_mfma_f32_16x16x32_bf16(af[mi], bf[ni], acc[mi][ni], 0, 0, 0); \
        }                                                                        \
        __syncthreads();                                                         \
    }

// ---------- QKV GEMM (M=8192, N=3072, K=1024) + fused RoPE/pack/V-transpose ---
// grid 24x64 = 1536 blocks; bijective XCD swizzle: XCD c owns 8 contiguous
// row-bands (x fastest within) -> A-panel resident per XCD.
__global__ __launch_bounds__(256) void gemm_qkv_fused(
        const unsigned short* __restrict__ A, const unsigned short* __restrict__ B,
        unsigned short* __restrict__ qb, unsigned short* __restrict__ kb,
        unsigned short* __restrict__ vb,
        const float* __restrict__ cosT, const float* __restrict__ sinT) {
    __shared__ __align__(16) unsigned short As[128 * 64];
    __shared__ __align__(16) unsigned short Bs[128 * 64];
    const int orig = blockIdx.y * 24 + blockIdx.x;
    const int swz  = (orig & 7) * 192 + (orig >> 3);
    const int bm = (swz / 24) << 7;
    const int bn = (swz % 24) << 7;
    GEMM_CORE(A, B, CDIM, bm, bn)

    const int nbase = bn + (wn << 6);
    const int mbase = bm + (wm << 6);
    const int b = mbase >> 11;
    const int tt0 = mbase & (TSEQ - 1);
    const int d0 = l15 << 2;          // 4 consecutive d per thread
    const int fi = l15 << 1;          // freq index base = d0/2

    if (nbase < 2 * CDIM) {
        const int isQ = (nbase < CDIM) ? 1 : 0;
        unsigned short* dst = isQ ? qb : kb;
        const float qs = isQ ? 0.18033688f : 1.0f;   // 0.125 * log2(e)
        const int h = (nbase & (CDIM - 1)) >> 6;
        unsigned short* hb = dst + (size_t)(b * NHEAD + h) * TSEQ * HDIM;
#pragma unroll
        for (int mi = 0; mi < 4; ++mi) {
#pragma unroll
            for (int r = 0; r < 4; ++r) {
                const int t = tt0 + (mi << 4) + (quad << 2) + r;
                float2 cc = *(const float2*)(cosT + (t << 5) + fi);
                float2 ss = *(const float2*)(sinT + (t << 5) + fi);
                float re0 = acc[mi][0][r], im0 = acc[mi][1][r];
                float re1 = acc[mi][2][r], im1 = acc[mi][3][r];
                union { unsigned short u[4]; uint2 v; } pk;
                pk.u[0] = f2bf((re0 * cc.x - im0 * ss.x) * qs);
                pk.u[1] = f2bf((re0 * ss.x + im0 * cc.x) * qs);
                pk.u[2] = f2bf((re1 * cc.y - im1 * ss.y) * qs);
                pk.u[3] = f2bf((re1 * ss.y + im1 * cc.y) * qs);
                *(uint2*)(hb + (size_t)t * HDIM + d0) = pk.v;
            }
        }
    } else {
        const int h = (nbase - 2 * CDIM) >> 6;
        unsigned short* hb = vb + (size_t)(b * NHEAD + h) * HDIM * TSEQ;
#pragma unroll
        for (int mi = 0; mi < 4; ++mi) {
            const int t0 = tt0 + (mi << 4) + (quad << 2);
#pragma unroll
            for (int ni = 0; ni < 4; ++ni) {
                const int d = d0 + ni;
                union { unsigned short u[4]; uint2 v; } pk;
#pragma unroll
                for (int r = 0; r < 4; ++r) pk.u[r] = f2bf(acc[mi][ni][r]);
                *(uint2*)(hb + (size_t)d * TSEQ + t0) = pk.v;
            }
        }
    }
}

// ---------- proj GEMM (M=8192, N=1024, K=1024), fp32 output, float4 stores ----
// grid 8x64 = 512 blocks; same XCD swizzle (64 ids/XCD = 8 row-bands).
__global__ __launch_bounds__(256) void gemm_proj(
        const unsigned short* __restrict__ A, const unsigned short* __restrict__ B,
        float* __restrict__ C) {
    __shared__ __align__(16) unsigned short As[128 * 64];
    __shared__ __align__(16) unsigned short Bs[128 * 64];
    const int orig = blockIdx.y * 8 + blockIdx.x;
    const int swz  = (orig & 7) * 64 + (orig >> 3);
    const int bm = (swz >> 3) << 7;
    const int bn = (swz & 7) << 7;
    GEMM_CORE(A, B, CDIM, bm, bn)

#pragma unroll
    for (int mi = 0; mi < 4; ++mi)
#pragma unroll
        for (int r = 0; r < 4; ++r) {
            const int row = bm + (wm << 6) + (mi << 4) + (quad << 2) + r;
            float4 v = make_float4(acc[mi][0][r], acc[mi][1][r], acc[mi][2][r], acc[mi][3][r]);
            *(float4*)(C + (size_t)row * CDIM + bn + (wn << 6) + (l15 << 2)) = v;
        }
}

// ---------------- Flash attention v4: swapped QK^T, zero-LDS softmax ----------
// S^T = mfma(A=K, B=Q): lane(l15,quad) gets S[q=ni*16+l15][key=16*mi+4*quad+r].
// The PV MFMA k-slot -> key mapping is chosen as pi(quad,j,kc)=16*(2kc+(j>>2))
// +4*quad+(j&3), so each lane's P A-fragment is PURELY LANE-LOCAL:
//   ap[ni][kc][j] = bf16(exp2(s[2kc+(j>>2)][ni][j&3]))   -- no LDS, no shuffle.
// V is staged with the matching column permutation col'=32*(m>>1)+8*q+4*(m&1)+r
// (key=16m+4q+r), so PV V-reads are single b128 with the proven chunk-XOR
// pattern. K staged with linear rows (sigma dropped; Ps gone).
// LDS: Ks[2]+Vs[2] = 32 KB (Ps' 32 KB freed). One barrier/kt (double buffer).
#define KTILE 64
#define NKT (TSEQ / KTILE)
#define QBLK 256
#define SWZ(row, ch) (((row) << 6) + ((((ch) ^ ((row) & 7))) << 3))
__global__ __launch_bounds__(256, 2) void attn_mfma(
        const unsigned short* __restrict__ qb, const unsigned short* __restrict__ kb,
        const unsigned short* __restrict__ vb, unsigned short* __restrict__ y) {
    const int bh = blockIdx.x;          // fast dim -> XCD L2 locality on K/V
    const int qt = blockIdx.y;
    const int b = bh >> 4, h = bh & 15;
    const int tid  = threadIdx.x;
    const int w    = tid >> 6;
    const int lane = tid & 63;
    const int l15  = lane & 15;
    const int quad = lane >> 4;

    __shared__ __align__(16) unsigned short Ks[2][KTILE * 64];
    __shared__ __align__(16) unsigned short Vs[2][HDIM * 64];

    // Q fragments (B-operand): aq[ni][kc] = Q[q=ni*16+l15][d=kc*32+quad*8+0..7]
    const size_t qoff = ((size_t)bh * TSEQ + qt * QBLK + w * 64) * HDIM;
    bf16x8 aq[4][2];
#pragma unroll
    for (int ni = 0; ni < 4; ++ni)
#pragma unroll
        for (int kc = 0; kc < 2; ++kc) {
            u32x4 v = *(const u32x4*)(qb + qoff + (size_t)(ni * 16 + l15) * HDIM + kc * 32 + quad * 8);
            aq[ni][kc] = __builtin_bit_cast(bf16x8, v);
        }

    f32x4 o[4][4];
    float l_r[4];   // partial row-sum for q=ni*16+l15 over this lane's (mi,r)
#pragma unroll
    for (int ni = 0; ni < 4; ++ni) {
        l_r[ni] = 0.f;
#pragma unroll
        for (int nc = 0; nc < 4; ++nc) o[ni][nc] = (f32x4){0.f, 0.f, 0.f, 0.f};
    }

    const unsigned short* kbase = kb + (size_t)bh * TSEQ * HDIM;
    const unsigned short* vbase = vb + (size_t)bh * HDIM * TSEQ;

    const int sr = tid >> 3;        // 0..31 (second element: +32)
    const int s8 = tid & 7;
    const int sp = s8 << 3;         // global col 0..56
    // K staging: linear rows sr / sr+32, col chunk s8
    const int stK0 = SWZ(sr, s8);
    const int stK1 = SWZ(sr + 32, s8);
    // V staging: sigma'd d-rows (row n holds true d=4*(n&15)+(n>>4)), permuted
    // key-cols col'=32*(m>>1)+8*q+4*(m&1)+r for key=16m+4q+r -> split b64 writes
    const int vrow0 = ((sr & 3) << 4) + (sr >> 2);
    const int vrow1 = vrow0 + 8;
    const int chV  = ((s8 >> 2) << 2) + ((s8 & 1) << 1);   // 4*(s>>2)+2*(s&1)
    const int offV = ((s8 >> 1) & 1) << 2;                 // 4*((s>>1)&1)
    const int e0 = vrow0 & 7;                              // == vrow1 & 7
    const int stV00 = (vrow0 << 6) + ((chV ^ e0) << 3) + offV;
    const int stV01 = (vrow0 << 6) + (((chV + 1) ^ e0) << 3) + offV;
    const int stV10 = (vrow1 << 6) + ((chV ^ e0) << 3) + offV;
    const int stV11 = (vrow1 << 6) + (((chV + 1) ^ e0) << 3) + offV;

    // prologue: tile 0 -> buf0; issue tile 1 loads
    u32x4 kr[2], vr[2];
#pragma unroll
    for (int l = 0; l < 2; ++l) {
        int idx = sr + (l << 5);
        kr[l] = *(const u32x4*)(kbase + (size_t)idx * HDIM + sp);
        vr[l] = *(const u32x4*)(vbase + (size_t)idx * TSEQ + sp);
    }
    *(u32x4*)&Ks[0][stK0] = kr[0];
    *(u32x4*)&Ks[0][stK1] = kr[1];
    *(uint2*)&Vs[0][stV00] = make_uint2(vr[0][0], vr[0][1]);
    *(uint2*)&Vs[0][stV01] = make_uint2(vr[0][2], vr[0][3]);
    *(uint2*)&Vs[0][stV10] = make_uint2(vr[1][0], vr[1][1]);
    *(uint2*)&Vs[0][stV11] = make_uint2(vr[1][2], vr[1][3]);
#pragma unroll
    for (int l = 0; l < 2; ++l) {
        int idx = sr + (l << 5);
        kr[l] = *(const u32x4*)(kbase + (size_t)(KTILE + idx) * HDIM + sp);
        vr[l] = *(const u32x4*)(vbase + (size_t)idx * TSEQ + KTILE + sp);
    }

    for (int kt = 0; kt < NKT; ++kt) {
        const int cur = kt & 1;
        __syncthreads();   // buf[cur] staged & visible; buf[cur^1] readers done

        // S^T = K Q (exp2 domain) + softmax + in-register P pack
        bf16x8 ap[4][2];
#pragma unroll
        for (int pvk = 0; pvk < 2; ++pvk) {
            f32x4 s[2][4];
#pragma unroll
            for (int mi2 = 0; mi2 < 2; ++mi2) {
                const int rowK = (pvk * 2 + mi2) * 16 + l15;
                bf16x8 k0 = __builtin_bit_cast(bf16x8, *(const u32x4*)&Ks[cur][SWZ(rowK, quad)]);
                bf16x8 k1 = __builtin_bit_cast(bf16x8, *(const u32x4*)&Ks[cur][SWZ(rowK, quad ^ 4)]);
#pragma unroll
                for (int ni = 0; ni < 4; ++ni) {
                    f32x4 a2 = (f32x4){0.f, 0.f, 0.f, 0.f};
                    a2 = __builtin_amdgcn_mfma_f32_16x16x32_bf16(k0, aq[ni][0], a2, 0, 0, 0);
                    a2 = __builtin_amdgcn_mfma_f32_16x16x32_bf16(k1, aq[ni][1], a2, 0, 0, 0);
                    s[mi2][ni] = a2;
                }
            }
#pragma unroll
            for (int ni = 0; ni < 4; ++ni) {
                float p0[4], p1[4];
#pragma unroll
                for (int r = 0; r < 4; ++r) {
                    p0[r] = __builtin_amdgcn_exp2f(s[0][ni][r]);
                    p1[r] = __builtin_amdgcn_exp2f(s[1][ni][r]);
                }
                l_r[ni] += ((p0[0] + p0[1]) + (p0[2] + p0[3]))
                         + ((p1[0] + p1[1]) + (p1[2] + p1[3]));
                u32x4 pk;
                pk[0] = __builtin_amdgcn_perm(__float_as_uint(p0[1]), __float_as_uint(p0[0]), 0x07060302u);
                pk[1] = __builtin_amdgcn_perm(__float_as_uint(p0[3]), __float_as_uint(p0[2]), 0x07060302u);
                pk[2] = __builtin_amdgcn_perm(__float_as_uint(p1[1]), __float_as_uint(p1[0]), 0x07060302u);
                pk[3] = __builtin_amdgcn_perm(__float_as_uint(p1[3]), __float_as_uint(p1[2]), 0x07060302u);
                ap[ni][pvk] = __builtin_bit_cast(bf16x8, pk);
            }
        }

        // stage next tile into buf^1; then issue tile kt+2 global loads
        if (kt + 1 < NKT) {
            const int nxt = cur ^ 1;
            *(u32x4*)&Ks[nxt][stK0] = kr[0];
            *(u32x4*)&Ks[nxt][stK1] = kr[1];
            *(uint2*)&Vs[nxt][stV00] = make_uint2(vr[0][0], vr[0][1]);
            *(uint2*)&Vs[nxt][stV01] = make_uint2(vr[0][2], vr[0][3]);
            *(uint2*)&Vs[nxt][stV10] = make_uint2(vr[1][0], vr[1][1]);
            *(uint2*)&Vs[nxt][stV11] = make_uint2(vr[1][2], vr[1][3]);
            if (kt + 2 < NKT) {
                int base = (kt + 2) * KTILE;
#pragma unroll
                for (int l = 0; l < 2; ++l) {
                    int idx = sr + (l << 5);
                    kr[l] = *(const u32x4*)(kbase + (size_t)(base + idx) * HDIM + sp);
                    vr[l] = *(const u32x4*)(vbase + (size_t)idx * TSEQ + base + sp);
                }
            }
        }

        // O += P V  (Vs col' order matches pi; d-rows sigma'd: col nc*16+l15 ->
        // true d=4*l15+nc)
#pragma unroll
        for (int nc = 0; nc < 4; ++nc) {
            const int rowV = nc * 16 + l15;
#pragma unroll
            for (int kc = 0; kc < 2; ++kc) {
                bf16x8 bv = __builtin_bit_cast(bf16x8,
                    *(const u32x4*)&Vs[cur][SWZ(rowV, (kc << 2) + quad)]);
#pragma unroll
                for (int ni = 0; ni < 4; ++ni)
                    o[ni][nc] = __builtin_amdgcn_mfma_f32_16x16x32_bf16(ap[ni][kc], bv, o[ni][nc], 0, 0, 0);
            }
        }
    }

    // l rowsum: reduce across the 4 quads (key dim spans quads now)
#pragma unroll
    for (int ni = 0; ni < 4; ++ni) {
        l_r[ni] += __shfl_xor(l_r[ni], 16, 64);
        l_r[ni] += __shfl_xor(l_r[ni], 32, 64);
    }
    // redistribute: o-row q=ni*16+quad*4+r needs l held at lanes l15=quad*4+r
    const int srcl = (quad << 4) + (quad << 2);
#pragma unroll
    for (int ni = 0; ni < 4; ++ni)
#pragma unroll
        for (int r = 0; r < 4; ++r) {
            float inv_l = 1.f / __shfl(l_r[ni], srcl + r, 64);
            int t = qt * QBLK + w * 64 + ni * 16 + quad * 4 + r;
            unsigned short* row = y + (size_t)(b * TSEQ + t) * CDIM + h * HDIM;
            union { unsigned short u[4]; uint2 v; } pk;
#pragma unroll
            for (int nc = 0; nc < 4; ++nc) pk.u[nc] = f2bf(o[ni][nc][r] * inv_l);
            *(uint2*)(row + (l15 << 2)) = pk.v;
        }
}

extern "C" void kernel_launch(void* const* d_in, const int* in_sizes, int n_in,
                              void* d_out, int out_size, void* d_ws, size_t ws_size,
                              hipStream_t stream) {
    const float* x      = (const float*)d_in[0];
    const float* w_attn = (const float*)d_in[1];
    const float* w_proj = (const float*)d_in[2];
    float* out = (float*)d_out;

    unsigned short* xb  = (unsigned short*)d_ws;
    unsigned short* wab = xb  + (size_t)M_ROWS * CDIM;
    unsigned short* wpb = wab + (size_t)3 * CDIM * CDIM;
    unsigned short* qb  = wpb + (size_t)CDIM * CDIM;
    unsigned short* kb  = qb  + (size_t)BATCH * NHEAD * TSEQ * HDIM;
    unsigned short* vb  = kb  + (size_t)BATCH * NHEAD * TSEQ * HDIM;
    unsigned short* yb  = vb  + (size_t)BATCH * NHEAD * TSEQ * HDIM;
    float* cosT = (float*)(yb + (size_t)M_ROWS * CDIM);
    float* sinT = cosT + TSEQ * (HDIM / 2);

    prep_kernel<<<6400, 256, 0, stream>>>(x, xb, w_attn, wab, w_proj, wpb, cosT, sinT);

    dim3 g1(3 * CDIM / 128, M_ROWS / 128);
    gemm_qkv_fused<<<g1, 256, 0, stream>>>(xb, wab, qb, kb, vb, cosT, sinT);

    dim3 g2(BATCH * NHEAD, TSEQ / QBLK);
    attn_mfma<<<g2, 256, 0, stream>>>(qb, kb, vb, yb);

    dim3 g3(CDIM / 128, M_ROWS / 128);
    gemm_proj<<<g3, 256, 0, stream>>>(yb, wpb, out);
}

// Round 10
// 234.193 us; speedup vs baseline: 1.1774x; 1.0343x over previous
//
#include <hip/hip_runtime.h>
#include <math.h>

#define BATCH 4
#define TSEQ 2048
#define CDIM 1024
#define NHEAD 16
#define HDIM 64
#define M_ROWS (BATCH * TSEQ)   // 8192

typedef float f32x4 __attribute__((ext_vector_type(4)));
typedef __bf16 bf16x8 __attribute__((ext_vector_type(8)));
typedef unsigned int u32x4 __attribute__((ext_vector_type(4)));

typedef const __attribute__((address_space(1))) void gas_void;
typedef __attribute__((address_space(3))) void las_void;

static __device__ __forceinline__ unsigned short f2bf(float f) {
    unsigned int x = __float_as_uint(f);
    x += 0x7fffu + ((x >> 16) & 1u);
    return (unsigned short)(x >> 16);
}

// ---------------- merged prep: 3x fp32->bf16 cvt + RoPE table -----------------
// block ranges: [0,4096) x, [4096,5632) w_attn, [5632,6144) w_proj, [6144,6400) rope
__global__ void prep_kernel(const float* __restrict__ x, unsigned short* __restrict__ xb,
                            const float* __restrict__ wa, unsigned short* __restrict__ wab,
                            const float* __restrict__ wp, unsigned short* __restrict__ wpb,
                            float* __restrict__ cosT, float* __restrict__ sinT) {
    int blk = blockIdx.x;
    if (blk < 6144) {
        const float* in;
        unsigned short* out;
        int base;
        if (blk < 4096)      { in = x;  out = xb;  base = blk; }
        else if (blk < 5632) { in = wa; out = wab; base = blk - 4096; }
        else                 { in = wp; out = wpb; base = blk - 5632; }
        int i = (base * 256 + threadIdx.x) << 3;
        float4 a = *(const float4*)(in + i);
        float4 b = *(const float4*)(in + i + 4);
        union { unsigned short u[8]; u32x4 v; } pk;
        pk.u[0] = f2bf(a.x); pk.u[1] = f2bf(a.y); pk.u[2] = f2bf(a.z); pk.u[3] = f2bf(a.w);
        pk.u[4] = f2bf(b.x); pk.u[5] = f2bf(b.y); pk.u[6] = f2bf(b.z); pk.u[7] = f2bf(b.w);
        *(u32x4*)(out + i) = pk.v;
    } else {
        int idx = (blk - 6144) * 256 + threadIdx.x;   // TSEQ * 32
        int t = idx >> 5;
        int i = idx & 31;
        double inv = pow(10000.0, -((double)(2 * i)) / (double)HDIM);
        double ph = (double)t * inv;
        cosT[idx] = (float)cos(ph);
        sinT[idx] = (float)sin(ph);
    }
}

// ============ bf16 MFMA GEMM core (C = A * B^T), 128x128 tile, BK=64 ==========
// v5: LDS chunk swizzle -> conflict-free fragment reads (6.29M -> 0 measured).
// v8: simple 2-barrier loop with BK=64 -- 83.7 -> 78.2us (counted-vmcnt
//     pipelines both regressed: T4-at-2-phase regime gate).
// v9: t-loop fully unrolled (addr immediates; VALUBusy 37.6->low) + bijective
//     XCD swizzle in callers. qkv dropped below attn (<75us).
#define GROW(p) (((p) & 64) + (((p) & 15) << 2) + (((p) >> 4) & 3))
#define GEMM_CORE(A_, B_, K_, bm_, bn_)                                          \
    const int tid = threadIdx.x;                                                 \
    const int w = tid >> 6, lane = tid & 63;                                     \
    const int l15 = lane & 15, quad = lane >> 4;                                 \
    const int wm = w >> 1, wn = w & 1;                                           \
    const int ksw = ((lane & 7) ^ ((lane >> 3) & 7)) << 3;                       \
    const int rx = l15 & 7;                                                      \
    const unsigned short* Ag[4]; const unsigned short* Bg[4];                    \
    unsigned short* Al[4]; unsigned short* Bl[4];                                \
    _Pragma("unroll")                                                            \
    for (int i = 0; i < 4; ++i) {                                                \
        const int row = (w << 5) + (i << 3) + (lane >> 3);                       \
        Ag[i] = A_ + (size_t)(bm_ + row) * K_ + ksw;                             \
        Bg[i] = B_ + (size_t)(bn_ + GROW(row)) * K_ + ksw;                       \
        Al[i] = As + row * 64 + ((lane & 7) << 3);                               \
        Bl[i] = Bs + row * 64 + ((lane & 7) << 3);                               \
    }                                                                            \
    f32x4 acc[4][4];                                                             \
    _Pragma("unroll")                                                            \
    for (int i = 0; i < 4; ++i)                                                  \
        _Pragma("unroll")                                                        \
        for (int j = 0; j < 4; ++j) acc[i][j] = (f32x4){0.f, 0.f, 0.f, 0.f};     \
    _Pragma("unroll")                                                            \
    for (int t = 0; t < K_ / 64; ++t) {                                          \
        _Pragma("unroll")                                                        \
        for (int i = 0; i < 4; ++i) {                                            \
            __builtin_amdgcn_global_load_lds((gas_void*)(Ag[i] + t * 64), (las_void*)Al[i], 16, 0, 0); \
            __builtin_amdgcn_global_load_lds((gas_void*)(Bg[i] + t * 64), (las_void*)Bl[i], 16, 0, 0); \
        }                                                                        \
        __syncthreads();                                                         \
        _Pragma("unroll")                                                        \
        for (int kk = 0; kk < 2; ++kk) {                                         \
            bf16x8 af[4], bf[4];                                                 \
            _Pragma("unroll")                                                    \
            for (int mi = 0; mi < 4; ++mi)                                       \
                af[mi] = __builtin_bit_cast(bf16x8,                              \
                    *(const u32x4*)(As + ((wm << 6) + (mi << 4) + l15) * 64 + ((((kk << 2) + quad) ^ rx) << 3))); \
            _Pragma("unroll")                                                    \
            for (int ni = 0; ni < 4; ++ni)                                       \
                bf[ni] = __builtin_bit_cast(bf16x8,                              \
                    *(const u32x4*)(Bs + ((wn << 6) + (ni << 4) + l15) * 64 + ((((kk << 2) + quad) ^ rx) << 3))); \
            _Pragma("unroll")                                                    \
            for (int mi = 0; mi < 4; ++mi)                                       \
                _Pragma("unroll")                                                \
                for (int ni = 0; ni < 4; ++ni)                                   \
                    acc[mi][ni] = __builtin_amdgcn_mfma_f32_16x16x32_bf16(af[mi], bf[ni], acc[mi][ni], 0, 0, 0); \
        }                                                                        \
        __syncthreads();                                                         \
    }

// ---------- QKV GEMM (M=8192, N=3072, K=1024) + fused RoPE/pack/V-transpose ---
// grid 24x64 = 1536 blocks; bijective XCD swizzle: XCD c owns 8 contiguous
// row-bands (x fastest within) -> A-panel resident per XCD.
__global__ __launch_bounds__(256) void gemm_qkv_fused(
        const unsigned short* __restrict__ A, const unsigned short* __restrict__ B,
        unsigned short* __restrict__ qb, unsigned short* __restrict__ kb,
        unsigned short* __restrict__ vb,
        const float* __restrict__ cosT, const float* __restrict__ sinT) {
    __shared__ __align__(16) unsigned short As[128 * 64];
    __shared__ __align__(16) unsigned short Bs[128 * 64];
    const int orig = blockIdx.y * 24 + blockIdx.x;
    const int swz  = (orig & 7) * 192 + (orig >> 3);
    const int bm = (swz / 24) << 7;
    const int bn = (swz % 24) << 7;
    GEMM_CORE(A, B, CDIM, bm, bn)

    const int nbase = bn + (wn << 6);
    const int mbase = bm + (wm << 6);
    const int b = mbase >> 11;
    const int tt0 = mbase & (TSEQ - 1);
    const int d0 = l15 << 2;          // 4 consecutive d per thread
    const int fi = l15 << 1;          // freq index base = d0/2

    if (nbase < 2 * CDIM) {
        const int isQ = (nbase < CDIM) ? 1 : 0;
        unsigned short* dst = isQ ? qb : kb;
        const float qs = isQ ? 0.18033688f : 1.0f;   // 0.125 * log2(e)
        const int h = (nbase & (CDIM - 1)) >> 6;
        unsigned short* hb = dst + (size_t)(b * NHEAD + h) * TSEQ * HDIM;
#pragma unroll
        for (int mi = 0; mi < 4; ++mi) {
#pragma unroll
            for (int r = 0; r < 4; ++r) {
                const int t = tt0 + (mi << 4) + (quad << 2) + r;
                float2 cc = *(const float2*)(cosT + (t << 5) + fi);
                float2 ss = *(const float2*)(sinT + (t << 5) + fi);
                float re0 = acc[mi][0][r], im0 = acc[mi][1][r];
                float re1 = acc[mi][2][r], im1 = acc[mi][3][r];
                union { unsigned short u[4]; uint2 v; } pk;
                pk.u[0] = f2bf((re0 * cc.x - im0 * ss.x) * qs);
                pk.u[1] = f2bf((re0 * ss.x + im0 * cc.x) * qs);
                pk.u[2] = f2bf((re1 * cc.y - im1 * ss.y) * qs);
                pk.u[3] = f2bf((re1 * ss.y + im1 * cc.y) * qs);
                *(uint2*)(hb + (size_t)t * HDIM + d0) = pk.v;
            }
        }
    } else {
        const int h = (nbase - 2 * CDIM) >> 6;
        unsigned short* hb = vb + (size_t)(b * NHEAD + h) * HDIM * TSEQ;
#pragma unroll
        for (int mi = 0; mi < 4; ++mi) {
            const int t0 = tt0 + (mi << 4) + (quad << 2);
#pragma unroll
            for (int ni = 0; ni < 4; ++ni) {
                const int d = d0 + ni;
                union { unsigned short u[4]; uint2 v; } pk;
#pragma unroll
                for (int r = 0; r < 4; ++r) pk.u[r] = f2bf(acc[mi][ni][r]);
                *(uint2*)(hb + (size_t)d * TSEQ + t0) = pk.v;
            }
        }
    }
}

// ---------- proj GEMM (M=8192, N=1024, K=1024), fp32 output, float4 stores ----
// grid 8x64 = 512 blocks; same XCD swizzle (64 ids/XCD = 8 row-bands).
__global__ __launch_bounds__(256) void gemm_proj(
        const unsigned short* __restrict__ A, const unsigned short* __restrict__ B,
        float* __restrict__ C) {
    __shared__ __align__(16) unsigned short As[128 * 64];
    __shared__ __align__(16) unsigned short Bs[128 * 64];
    const int orig = blockIdx.y * 8 + blockIdx.x;
    const int swz  = (orig & 7) * 64 + (orig >> 3);
    const int bm = (swz >> 3) << 7;
    const int bn = (swz & 7) << 7;
    GEMM_CORE(A, B, CDIM, bm, bn)

#pragma unroll
    for (int mi = 0; mi < 4; ++mi)
#pragma unroll
        for (int r = 0; r < 4; ++r) {
            const int row = bm + (wm << 6) + (mi << 4) + (quad << 2) + r;
            float4 v = make_float4(acc[mi][0][r], acc[mi][1][r], acc[mi][2][r], acc[mi][3][r]);
            *(float4*)(C + (size_t)row * CDIM + bn + (wn << 6) + (l15 << 2)) = v;
        }
}

// ---------------- Flash attention v5: swapped QK^T, zero-LDS softmax ----------
// v4 (r4): S^T = mfma(A=K, B=Q); P A-fragments lane-local; V col-permuted;
//          Ps LDS round-trip eliminated. 90 -> 75.6us.
// v5 (this round):
//  (a) V-staging bank fix [1,048,576 conflicts -> 0]: v4's b64 V writes hit
//      only 16 banks/quarter-wave because both staged d-rows in a quarter
//      share e0=vrow&7 (even chunks only). The thread->d-row assignment is a
//      free permutation: fv = (sr&24)|((sr&1)<<2)|((sr>>1)&3) gives the two
//      rows of each quarter opposite e0 parity -> even+odd chunks -> all 32
//      banks, 1 word/bank, conflict-free. Read side unchanged (same sigma_d).
//  (b) l = P*1 via MFMA-ones: lac[ni] = mfma(ap[ni][kc], ones) replaces 56
//      VALU adds/iter + 24 epilogue shuffles with 8 MFMAs/iter. C-layout gives
//      lane(l15,quad) reg r = l[q=ni*16+4*quad+r] -- exactly the epilogue's q.
//      Denominator now sums the SAME truncated-bf16 P as the PV numerator
//      (weights sum to exactly 1 in P-tilde space).
#define KTILE 64
#define NKT (TSEQ / KTILE)
#define QBLK 256
#define SWZ(row, ch) (((row) << 6) + ((((ch) ^ ((row) & 7))) << 3))
__global__ __launch_bounds__(256, 2) void attn_mfma(
        const unsigned short* __restrict__ qb, const unsigned short* __restrict__ kb,
        const unsigned short* __restrict__ vb, unsigned short* __restrict__ y) {
    const int bh = blockIdx.x;          // fast dim -> XCD L2 locality on K/V
    const int qt = blockIdx.y;
    const int b = bh >> 4, h = bh & 15;
    const int tid  = threadIdx.x;
    const int w    = tid >> 6;
    const int lane = tid & 63;
    const int l15  = lane & 15;
    const int quad = lane >> 4;

    __shared__ __align__(16) unsigned short Ks[2][KTILE * 64];
    __shared__ __align__(16) unsigned short Vs[2][HDIM * 64];

    // Q fragments (B-operand): aq[ni][kc] = Q[q=ni*16+l15][d=kc*32+quad*8+0..7]
    const size_t qoff = ((size_t)bh * TSEQ + qt * QBLK + w * 64) * HDIM;
    bf16x8 aq[4][2];
#pragma unroll
    for (int ni = 0; ni < 4; ++ni)
#pragma unroll
        for (int kc = 0; kc < 2; ++kc) {
            u32x4 v = *(const u32x4*)(qb + qoff + (size_t)(ni * 16 + l15) * HDIM + kc * 32 + quad * 8);
            aq[ni][kc] = __builtin_bit_cast(bf16x8, v);
        }

    // all-ones bf16x8 for the l = P*1 rowsum MFMA
    const u32x4 ones_u = (u32x4){0x3F803F80u, 0x3F803F80u, 0x3F803F80u, 0x3F803F80u};
    const bf16x8 vone = __builtin_bit_cast(bf16x8, ones_u);

    f32x4 o[4][4];
    f32x4 lac[4];   // lac[ni][r] = l[q = ni*16 + 4*quad + r] (all l15 lanes)
#pragma unroll
    for (int ni = 0; ni < 4; ++ni) {
        lac[ni] = (f32x4){0.f, 0.f, 0.f, 0.f};
#pragma unroll
        for (int nc = 0; nc < 4; ++nc) o[ni][nc] = (f32x4){0.f, 0.f, 0.f, 0.f};
    }

    const unsigned short* kbase = kb + (size_t)bh * TSEQ * HDIM;
    const unsigned short* vbase = vb + (size_t)bh * HDIM * TSEQ;

    const int sr = tid >> 3;        // 0..31 (second element: +32)
    const int s8 = tid & 7;
    const int sp = s8 << 3;         // global col 0..56
    // K staging: linear rows sr / sr+32, col chunk s8
    const int stK0 = SWZ(sr, s8);
    const int stK1 = SWZ(sr + 32, s8);
    // V row assignment: fv bit-remap so each quarter-wave's two rows differ in
    // e0 parity (bank fix); logical rows via sigma_d (row n <-> true d).
    const int fv = (sr & 24) | ((sr & 1) << 2) | ((sr >> 1) & 3);
    const int vrow0 = ((fv & 3) << 4) + (fv >> 2);
    const int vrow1 = vrow0 + 8;
    const int chV  = ((s8 >> 2) << 2) + ((s8 & 1) << 1);   // 4*(s>>2)+2*(s&1)
    const int offV = ((s8 >> 1) & 1) << 2;                 // 4*((s>>1)&1)
    const int e0 = vrow0 & 7;                              // == vrow1 & 7
    const int stV00 = (vrow0 << 6) + ((chV ^ e0) << 3) + offV;
    const int stV01 = (vrow0 << 6) + (((chV + 1) ^ e0) << 3) + offV;
    const int stV10 = (vrow1 << 6) + ((chV ^ e0) << 3) + offV;
    const int stV11 = (vrow1 << 6) + (((chV + 1) ^ e0) << 3) + offV;

    // prologue: tile 0 -> buf0; issue tile 1 loads
    u32x4 kr[2], vr[2];
#pragma unroll
    for (int l = 0; l < 2; ++l) {
        kr[l] = *(const u32x4*)(kbase + (size_t)(sr + (l << 5)) * HDIM + sp);
        vr[l] = *(const u32x4*)(vbase + (size_t)(fv + (l << 5)) * TSEQ + sp);
    }
    *(u32x4*)&Ks[0][stK0] = kr[0];
    *(u32x4*)&Ks[0][stK1] = kr[1];
    *(uint2*)&Vs[0][stV00] = make_uint2(vr[0][0], vr[0][1]);
    *(uint2*)&Vs[0][stV01] = make_uint2(vr[0][2], vr[0][3]);
    *(uint2*)&Vs[0][stV10] = make_uint2(vr[1][0], vr[1][1]);
    *(uint2*)&Vs[0][stV11] = make_uint2(vr[1][2], vr[1][3]);
#pragma unroll
    for (int l = 0; l < 2; ++l) {
        kr[l] = *(const u32x4*)(kbase + (size_t)(KTILE + sr + (l << 5)) * HDIM + sp);
        vr[l] = *(const u32x4*)(vbase + (size_t)(fv + (l << 5)) * TSEQ + KTILE + sp);
    }

    for (int kt = 0; kt < NKT; ++kt) {
        const int cur = kt & 1;
        __syncthreads();   // buf[cur] staged & visible; buf[cur^1] readers done

        // S^T = K Q (exp2 domain) + softmax + in-register P pack
        bf16x8 ap[4][2];
#pragma unroll
        for (int pvk = 0; pvk < 2; ++pvk) {
            f32x4 s[2][4];
#pragma unroll
            for (int mi2 = 0; mi2 < 2; ++mi2) {
                const int rowK = (pvk * 2 + mi2) * 16 + l15;
                bf16x8 k0 = __builtin_bit_cast(bf16x8, *(const u32x4*)&Ks[cur][SWZ(rowK, quad)]);
                bf16x8 k1 = __builtin_bit_cast(bf16x8, *(const u32x4*)&Ks[cur][SWZ(rowK, quad ^ 4)]);
#pragma unroll
                for (int ni = 0; ni < 4; ++ni) {
                    f32x4 a2 = (f32x4){0.f, 0.f, 0.f, 0.f};
                    a2 = __builtin_amdgcn_mfma_f32_16x16x32_bf16(k0, aq[ni][0], a2, 0, 0, 0);
                    a2 = __builtin_amdgcn_mfma_f32_16x16x32_bf16(k1, aq[ni][1], a2, 0, 0, 0);
                    s[mi2][ni] = a2;
                }
            }
#pragma unroll
            for (int ni = 0; ni < 4; ++ni) {
                float p0[4], p1[4];
#pragma unroll
                for (int r = 0; r < 4; ++r) {
                    p0[r] = __builtin_amdgcn_exp2f(s[0][ni][r]);
                    p1[r] = __builtin_amdgcn_exp2f(s[1][ni][r]);
                }
                u32x4 pk;
                pk[0] = __builtin_amdgcn_perm(__float_as_uint(p0[1]), __float_as_uint(p0[0]), 0x07060302u);
                pk[1] = __builtin_amdgcn_perm(__float_as_uint(p0[3]), __float_as_uint(p0[2]), 0x07060302u);
                pk[2] = __builtin_amdgcn_perm(__float_as_uint(p1[1]), __float_as_uint(p1[0]), 0x07060302u);
                pk[3] = __builtin_amdgcn_perm(__float_as_uint(p1[3]), __float_as_uint(p1[2]), 0x07060302u);
                ap[ni][pvk] = __builtin_bit_cast(bf16x8, pk);
            }
        }

        // stage next tile into buf^1; then issue tile kt+2 global loads
        if (kt + 1 < NKT) {
            const int nxt = cur ^ 1;
            *(u32x4*)&Ks[nxt][stK0] = kr[0];
            *(u32x4*)&Ks[nxt][stK1] = kr[1];
            *(uint2*)&Vs[nxt][stV00] = make_uint2(vr[0][0], vr[0][1]);
            *(uint2*)&Vs[nxt][stV01] = make_uint2(vr[0][2], vr[0][3]);
            *(uint2*)&Vs[nxt][stV10] = make_uint2(vr[1][0], vr[1][1]);
            *(uint2*)&Vs[nxt][stV11] = make_uint2(vr[1][2], vr[1][3]);
            if (kt + 2 < NKT) {
                int base = (kt + 2) * KTILE;
#pragma unroll
                for (int l = 0; l < 2; ++l) {
                    kr[l] = *(const u32x4*)(kbase + (size_t)(base + sr + (l << 5)) * HDIM + sp);
                    vr[l] = *(const u32x4*)(vbase + (size_t)(fv + (l << 5)) * TSEQ + base + sp);
                }
            }
        }

        // l += P * 1 (rowsum via matrix pipe; replaces VALU adds + shuffles)
#pragma unroll
        for (int ni = 0; ni < 4; ++ni) {
            lac[ni] = __builtin_amdgcn_mfma_f32_16x16x32_bf16(ap[ni][0], vone, lac[ni], 0, 0, 0);
            lac[ni] = __builtin_amdgcn_mfma_f32_16x16x32_bf16(ap[ni][1], vone, lac[ni], 0, 0, 0);
        }

        // O += P V  (Vs col' order matches pi; d-rows sigma'd: col nc*16+l15 ->
        // true d=4*l15+nc)
#pragma unroll
        for (int nc = 0; nc < 4; ++nc) {
            const int rowV = nc * 16 + l15;
#pragma unroll
            for (int kc = 0; kc < 2; ++kc) {
                bf16x8 bv = __builtin_bit_cast(bf16x8,
                    *(const u32x4*)&Vs[cur][SWZ(rowV, (kc << 2) + quad)]);
#pragma unroll
                for (int ni = 0; ni < 4; ++ni)
                    o[ni][nc] = __builtin_amdgcn_mfma_f32_16x16x32_bf16(ap[ni][kc], bv, o[ni][nc], 0, 0, 0);
            }
        }
    }

    // epilogue: O /= l; lac[ni][r] is already this lane's l[q] -- no shuffles
#pragma unroll
    for (int ni = 0; ni < 4; ++ni)
#pragma unroll
        for (int r = 0; r < 4; ++r) {
            float inv_l = 1.f / lac[ni][r];
            int t = qt * QBLK + w * 64 + ni * 16 + quad * 4 + r;
            unsigned short* row = y + (size_t)(b * TSEQ + t) * CDIM + h * HDIM;
            union { unsigned short u[4]; uint2 v; } pk;
#pragma unroll
            for (int nc = 0; nc < 4; ++nc) pk.u[nc] = f2bf(o[ni][nc][r] * inv_l);
            *(uint2*)(row + (l15 << 2)) = pk.v;
        }
}

extern "C" void kernel_launch(void* const* d_in, const int* in_sizes, int n_in,
                              void* d_out, int out_size, void* d_ws, size_t ws_size,
                              hipStream_t stream) {
    const float* x      = (const float*)d_in[0];
    const float* w_attn = (const float*)d_in[1];
    const float* w_proj = (const float*)d_in[2];
    float* out = (float*)d_out;

    unsigned short* xb  = (unsigned short*)d_ws;
    unsigned short* wab = xb  + (size_t)M_ROWS * CDIM;
    unsigned short* wpb = wab + (size_t)3 * CDIM * CDIM;
    unsigned short* qb  = wpb + (size_t)CDIM * CDIM;
    unsigned short* kb  = qb  + (size_t)BATCH * NHEAD * TSEQ * HDIM;
    unsigned short* vb  = kb  + (size_t)BATCH * NHEAD * TSEQ * HDIM;
    unsigned short* yb  = vb  + (size_t)BATCH * NHEAD * TSEQ * HDIM;
    float* cosT = (float*)(yb + (size_t)M_ROWS * CDIM);
    float* sinT = cosT + TSEQ * (HDIM / 2);

    prep_kernel<<<6400, 256, 0, stream>>>(x, xb, w_attn, wab, w_proj, wpb, cosT, sinT);

    dim3 g1(3 * CDIM / 128, M_ROWS / 128);
    gemm_qkv_fused<<<g1, 256, 0, stream>>>(xb, wab, qb, kb, vb, cosT, sinT);

    dim3 g2(BATCH * NHEAD, TSEQ / QBLK);
    attn_mfma<<<g2, 256, 0, stream>>>(qb, kb, vb, yb);

    dim3 g3(CDIM / 128, M_ROWS / 128);
    gemm_proj<<<g3, 256, 0, stream>>>(yb, wpb, out);
}